// Round 1
// baseline (173.569 us; speedup 1.0000x reference)
//
#include <hip/hip_runtime.h>

#define B_   4
#define CIN  64
#define COUT 64
#define H_   128
#define W_   128
#define KK   9
#define KTOT 576           // CIN*KK
#define PIX  (B_*H_*W_)    // 65536
#define MTILE 32
#define NBLK (PIX / MTILE) // 2048
#define ROWB 1152          // LDS row stride in bytes (576 bf16)

typedef short bf16x8 __attribute__((ext_vector_type(8)));
typedef float f32x4  __attribute__((ext_vector_type(4)));

__device__ __forceinline__ unsigned short f2bf(float f) {
    unsigned int u = __float_as_uint(f);
    u = (u + 0x7FFFu + ((u >> 16) & 1u)) >> 16;
    return (unsigned short)u;
}
__device__ __forceinline__ float bf2f(unsigned short s) {
    return __uint_as_float(((unsigned int)s) << 16);
}

// ---- Kernel 1: x (B,CIN,H,W) f32 -> xt (B,H,W,CIN) bf16 (channels-last) ----
__global__ __launch_bounds__(256) void k_transpose(const float* __restrict__ x,
                                                   unsigned short* __restrict__ xt) {
    __shared__ float lds[64 * 129];
    int bi = blockIdx.x;            // b*H + i
    int b = bi >> 7, i = bi & 127;
    int tid = threadIdx.x;
#pragma unroll
    for (int cc = 0; cc < 32; ++cc) {
        int c = cc * 2 + (tid >> 7);
        int w = tid & 127;
        lds[c * 129 + w] = x[((b * CIN + c) * H_ + i) * W_ + w];
    }
    __syncthreads();
#pragma unroll
    for (int q = 0; q < 32; ++q) {
        int c = tid & 63;
        int w = q * 4 + (tid >> 6);
        xt[((b * H_ + i) * W_ + w) * CIN + c] = f2bf(lds[c * 129 + w]);
    }
}

// ---- Kernel 2: weight (COUT,CIN,3,3) f32 -> B-fragment-ordered bf16 ----
// wtf[s][ntile][lane][j] = W[n][c][kpos]
//   kg = s*32 + (lane>>4)*8 + j   (K index, ordering kg = kpos*64 + c)
//   n  = ntile*16 + (lane&15)
__global__ __launch_bounds__(256) void k_weight(const float* __restrict__ w,
                                                unsigned short* __restrict__ wtf) {
    int t = blockIdx.x * 256 + threadIdx.x;
    if (t >= 18 * 4 * 64 * 8) return;
    int j    = t & 7;
    int lane = (t >> 3) & 63;
    int nt   = (t >> 9) & 3;
    int s    = t >> 11;
    int kg   = s * 32 + ((lane >> 4) << 3) + j;
    int n    = nt * 16 + (lane & 15);
    int kpos = kg >> 6, c = kg & 63;
    wtf[t] = f2bf(w[(n * CIN + c) * 9 + kpos]);
}

// ---- Main: sample+modulate into LDS (bf16), then MFMA GEMM ----
__global__ __launch_bounds__(256, 4) void k_main(
    const unsigned short* __restrict__ xt,
    const float* __restrict__ offset,
    const float* __restrict__ mask,
    const unsigned short* __restrict__ wtf,
    const float* __restrict__ bias,
    float* __restrict__ out) {
    __shared__ __align__(128) unsigned char v_lds[MTILE * ROWB];
    const int tid  = threadIdx.x;
    const int lane = tid & 63;
    const int wv   = tid >> 6;
    const int g0   = blockIdx.x * MTILE;

    // -------- sampling phase: lane = input channel --------
    for (int idx = wv; idx < MTILE * KK; idx += 4) {
        int p = idx / 9;
        int k = idx - p * 9;
        int g = g0 + p;
        int b = g >> 14, i = (g >> 7) & 127, j = g & 127;
        int hw = i * W_ + j;
        float offi = offset[(b * 18 + 2 * k) * (H_ * W_) + hw];
        float offj = offset[(b * 18 + 2 * k + 1) * (H_ * W_) + hw];
        float msk  = mask[(b * 9 + k) * (H_ * W_) + hw];
        float ci = offi + (float)(i + k / 3 - 1);
        float cj = offj + (float)(j + (k % 3) - 1);
        float fli = floorf(ci), flj = floorf(cj);
        int li = (int)fli, lj = (int)flj;
        float fi = ci - fli, fj = cj - flj;
        int li1 = li + 1, lj1 = lj + 1;
        bool vy0 = (li  >= 0) && (li  < H_);
        bool vy1 = (li1 >= 0) && (li1 < H_);
        bool vx0 = (lj  >= 0) && (lj  < W_);
        bool vx1 = (lj1 >= 0) && (lj1 < W_);
        int y0 = min(max(li, 0), H_ - 1),  y1 = min(max(li1, 0), H_ - 1);
        int x0 = min(max(lj, 0), W_ - 1),  x1 = min(max(lj1, 0), W_ - 1);
        const unsigned short* xb = xt + (size_t)b * (H_ * W_ * CIN) + lane;
        float v00 = (vy0 && vx0) ? bf2f(xb[(y0 * W_ + x0) * CIN]) : 0.f;
        float v01 = (vy0 && vx1) ? bf2f(xb[(y0 * W_ + x1) * CIN]) : 0.f;
        float v10 = (vy1 && vx0) ? bf2f(xb[(y1 * W_ + x0) * CIN]) : 0.f;
        float v11 = (vy1 && vx1) ? bf2f(xb[(y1 * W_ + x1) * CIN]) : 0.f;
        float vt = v00 + fj * (v01 - v00);
        float vb = v10 + fj * (v11 - v10);
        float v  = (vt + fi * (vb - vt)) * msk;
        int saddr = p * ROWB + (k * 64 + lane) * 2;
        saddr ^= ((p & 7) << 4);                    // T2 XOR swizzle (16B units)
        *(unsigned short*)(v_lds + saddr) = f2bf(v);
    }
    __syncthreads();

    // -------- MFMA phase: wave wv owns n-tile wv (16 couts), both m-tiles --------
    f32x4 acc0 = {0.f, 0.f, 0.f, 0.f};
    f32x4 acc1 = {0.f, 0.f, 0.f, 0.f};
    const bf16x8* wp = (const bf16x8*)wtf;
    const int r0 = lane & 15;            // A row within tile
    const int kb = (lane >> 4) << 4;     // k-group byte offset
    const int sw = (r0 & 7) << 4;        // same swizzle for both m-tiles (16 ≡ 0 mod 8)
#pragma unroll
    for (int s = 0; s < 18; ++s) {
        bf16x8 a0 = *(const bf16x8*)(v_lds + ((r0 * ROWB + s * 64 + kb) ^ sw));
        bf16x8 a1 = *(const bf16x8*)(v_lds + (((r0 + 16) * ROWB + s * 64 + kb) ^ sw));
        bf16x8 b0 = wp[(s * 4 + wv) * 64 + lane];
        acc0 = __builtin_amdgcn_mfma_f32_16x16x32_bf16(a0, b0, acc0, 0, 0, 0);
        acc1 = __builtin_amdgcn_mfma_f32_16x16x32_bf16(a1, b0, acc1, 0, 0, 0);
    }

    // -------- epilogue: C/D map col=lane&15 (=n), row=(lane>>4)*4+r (=m) --------
    int n = wv * 16 + (lane & 15);
    float bs = bias[n];
#pragma unroll
    for (int r = 0; r < 4; ++r) {
        int p0 = ((lane >> 4) << 2) + r;
        {
            int g = g0 + p0;
            int b = g >> 14, i = (g >> 7) & 127, j = g & 127;
            out[((b * COUT + n) * H_ + i) * W_ + j] = acc0[r] + bs;
        }
        {
            int g = g0 + 16 + p0;
            int b = g >> 14, i = (g >> 7) & 127, j = g & 127;
            out[((b * COUT + n) * H_ + i) * W_ + j] = acc1[r] + bs;
        }
    }
}

extern "C" void kernel_launch(void* const* d_in, const int* in_sizes, int n_in,
                              void* d_out, int out_size, void* d_ws, size_t ws_size,
                              hipStream_t stream) {
    const float* x      = (const float*)d_in[0];
    const float* offset = (const float*)d_in[1];
    const float* mask   = (const float*)d_in[2];
    const float* weight = (const float*)d_in[3];
    const float* bias   = (const float*)d_in[4];
    float* out = (float*)d_out;
    unsigned short* xt  = (unsigned short*)d_ws;
    unsigned short* wtf = xt + (size_t)B_ * H_ * W_ * CIN;   // +8 MB

    k_transpose<<<B_ * H_, 256, 0, stream>>>(x, xt);
    k_weight<<<144, 256, 0, stream>>>(weight, wtf);
    k_main<<<NBLK, 256, 0, stream>>>(xt, offset, mask, wtf, bias, out);
}

// Round 2
// 57.485 us; speedup vs baseline: 3.0194x; 3.0194x over previous
//
#include <hip/hip_runtime.h>

#define B_   4
#define CIN  64
#define COUT 64
#define H_   128
#define W_   128
#define HW   (H_*W_)
#define KK   9
#define PIX  (B_*H_*W_)    // 65536
#define MTILE 32
#define NBLK (PIX / MTILE) // 2048

typedef short bf16x8 __attribute__((ext_vector_type(8)));
typedef float f32x4  __attribute__((ext_vector_type(4)));
typedef int   i32x4  __attribute__((ext_vector_type(4)));
typedef unsigned int u32x4 __attribute__((ext_vector_type(4)));
typedef unsigned int u32;

__device__ __forceinline__ unsigned short f2bf(float f) {
    unsigned int u = __float_as_uint(f);
    u = (u + 0x7FFFu + ((u >> 16) & 1u)) >> 16;
    return (unsigned short)u;
}

// ---- Kernel 1: x (B,CIN,H,W) f32 -> xt (B,H,W,CIN) bf16 (channels-last) ----
__global__ __launch_bounds__(256) void k_transpose(const float* __restrict__ x,
                                                   unsigned short* __restrict__ xt) {
    __shared__ float lds[64 * 129];
    int bi = blockIdx.x;            // b*H + i
    int b = bi >> 7, i = bi & 127;
    int tid = threadIdx.x;
#pragma unroll
    for (int cc = 0; cc < 32; ++cc) {
        int c = cc * 2 + (tid >> 7);
        int w = tid & 127;
        lds[c * 129 + w] = x[((b * CIN + c) * H_ + i) * W_ + w];
    }
    __syncthreads();
#pragma unroll
    for (int q = 0; q < 32; ++q) {
        int c = tid & 63;
        int w = q * 4 + (tid >> 6);
        xt[((b * H_ + i) * W_ + w) * CIN + c] = f2bf(lds[c * 129 + w]);
    }
}

// ---- Kernel 2: weight (COUT,CIN,3,3) f32 -> B-fragment-ordered bf16 ----
// wtf[s][ntile][lane][j] = W[n][c][kpos];  kg = s*32 + (lane>>4)*8 + j = kpos*64 + c
__global__ __launch_bounds__(256) void k_weight(const float* __restrict__ w,
                                                unsigned short* __restrict__ wtf) {
    int t = blockIdx.x * 256 + threadIdx.x;
    if (t >= 18 * 4 * 64 * 8) return;
    int j    = t & 7;
    int lane = (t >> 3) & 63;
    int nt   = (t >> 9) & 3;
    int s    = t >> 11;
    int kg   = s * 32 + ((lane >> 4) << 3) + j;
    int n    = nt * 16 + (lane & 15);
    int kpos = kg >> 6, c = kg & 63;
    wtf[t] = f2bf(w[(n * CIN + c) * 9 + kpos]);
}

// ---- per-(pixel,kpoint) metadata: 4 clamped byte-offsets + 4 weights ----
// validity folded into weights (invalid corner -> weight 0, address clamped)
__device__ __forceinline__ void compute_meta(
    int pt, int b, int i, int j0,
    const float* __restrict__ offset, const float* __restrict__ mask,
    i32x4* meta_a, f32x4* meta_w) {
    int kp = pt >> 5;        // 0..8
    int p  = pt & 31;
    int hw = i * W_ + j0 + p;
    float offi = offset[(b * 18 + 2 * kp) * HW + hw];
    float offj = offset[(b * 18 + 2 * kp + 1) * HW + hw];
    float msk  = mask[(b * KK + kp) * HW + hw];
    float ci = offi + (float)(i + kp / 3 - 1);
    float cj = offj + (float)(j0 + p + kp % 3 - 1);
    float fli = floorf(ci), flj = floorf(cj);
    float fi = ci - fli, fj = cj - flj;
    int li = (int)fli, lj = (int)flj;
    int li1 = li + 1, lj1 = lj + 1;
    float vy0 = (li  >= 0 && li  < H_) ? 1.f : 0.f;
    float vy1 = (li1 >= 0 && li1 < H_) ? 1.f : 0.f;
    float vx0 = (lj  >= 0 && lj  < W_) ? 1.f : 0.f;
    float vx1 = (lj1 >= 0 && lj1 < W_) ? 1.f : 0.f;
    int y0 = min(max(li,  0), H_ - 1), y1 = min(max(li1, 0), H_ - 1);
    int x0 = min(max(lj,  0), W_ - 1), x1 = min(max(lj1, 0), W_ - 1);
    float gi  = fi * msk;
    float gj  = fj * msk;
    float w11 = gi * fj;              // fi*fj*m
    float w10 = gi - w11;             // fi*(1-fj)*m
    float w01 = gj - w11;             // (1-fi)*fj*m
    float w00 = msk - gi - gj + w11;  // (1-fi)*(1-fj)*m
    i32x4 a; f32x4 w;
    a.x = (y0 * W_ + x0) * (CIN * 2); w.x = w00 * vy0 * vx0;
    a.y = (y0 * W_ + x1) * (CIN * 2); w.y = w01 * vy0 * vx1;
    a.z = (y1 * W_ + x0) * (CIN * 2); w.z = w10 * vy1 * vx0;
    a.w = (y1 * W_ + x1) * (CIN * 2); w.w = w11 * vy1 * vx1;
    meta_a[pt] = a; meta_w[pt] = w;
}

// ---- Main: metadata -> fragment-granularity gather+blend -> MFMA GEMM ----
__global__ __launch_bounds__(256, 3) void k_main(
    const unsigned short* __restrict__ xt,
    const float* __restrict__ offset,
    const float* __restrict__ mask,
    const unsigned short* __restrict__ wtf,
    const float* __restrict__ bias,
    float* __restrict__ out) {
    __shared__ i32x4 meta_a[MTILE * KK];               // 4.5 KB
    __shared__ f32x4 meta_w[MTILE * KK];               // 4.5 KB
    __shared__ __align__(16) bf16x8 a_lds[18 * 2 * 64]; // [s][mt][lane], 36 KB

    const int tid  = threadIdx.x;
    const int lane = tid & 63;
    const int wv   = tid >> 6;
    const int g0   = blockIdx.x * MTILE;
    const int b  = g0 >> 14;
    const int i  = (g0 >> 7) & 127;
    const int j0 = g0 & 127;

    // -------- phase 0: metadata, one thread per (pixel, kpoint) --------
    compute_meta(tid, b, i, j0, offset, mask, meta_a, meta_w);
    if (tid < 32) compute_meta(256 + tid, b, i, j0, offset, mask, meta_a, meta_w);
    __syncthreads();

    // -------- phase 1: gather + blend, one lane = one 16B A-fragment --------
    const char* xb = (const char*)(xt + (size_t)b * (HW * CIN));
    const int cb = (lane >> 4) * 16;   // ch-group byte offset within 128B pixel chunk
#pragma unroll 3
    for (int t = 0; t < 9; ++t) {
        int fid = wv * 9 + t;                 // 36 fragments, 9 per wave
        int kp = fid >> 2, mt = (fid >> 1) & 1, h = fid & 1;
        int pt = kp * 32 + mt * 16 + (lane & 15);
        i32x4 ao = meta_a[pt];
        f32x4 wt = meta_w[pt];
        int cof = cb + h * 64;                // +32 channels for second k-half
        u32x4 q00 = *(const u32x4*)(xb + ao.x + cof);
        u32x4 q01 = *(const u32x4*)(xb + ao.y + cof);
        u32x4 q10 = *(const u32x4*)(xb + ao.z + cof);
        u32x4 q11 = *(const u32x4*)(xb + ao.w + cof);
        u32x4 po;
#pragma unroll
        for (int q = 0; q < 4; ++q) {
            float l00 = __uint_as_float(q00[q] << 16);
            float l01 = __uint_as_float(q01[q] << 16);
            float l10 = __uint_as_float(q10[q] << 16);
            float l11 = __uint_as_float(q11[q] << 16);
            float h00 = __uint_as_float(q00[q] & 0xFFFF0000u);
            float h01 = __uint_as_float(q01[q] & 0xFFFF0000u);
            float h10 = __uint_as_float(q10[q] & 0xFFFF0000u);
            float h11 = __uint_as_float(q11[q] & 0xFFFF0000u);
            float rl = wt.x * l00 + wt.y * l01 + wt.z * l10 + wt.w * l11;
            float rh = wt.x * h00 + wt.y * h01 + wt.z * h10 + wt.w * h11;
            // round-half-up to bf16, pack high halves: [bf16(rh)][bf16(rl)]
            po[q] = __builtin_amdgcn_perm(__float_as_uint(rh) + 0x8000u,
                                          __float_as_uint(rl) + 0x8000u,
                                          0x07060302u);
        }
        *(u32x4*)&a_lds[((kp * 2 + h) * 2 + mt) * 64 + lane] = po;
    }
    __syncthreads();

    // -------- phase 2: MFMA, wave wv owns n-tile wv (16 couts), both m-tiles --------
    f32x4 acc0 = {0.f, 0.f, 0.f, 0.f};
    f32x4 acc1 = {0.f, 0.f, 0.f, 0.f};
    const bf16x8* wp = (const bf16x8*)wtf;
#pragma unroll 6
    for (int s = 0; s < 18; ++s) {
        bf16x8 a0 = a_lds[(s * 2 + 0) * 64 + lane];
        bf16x8 a1 = a_lds[(s * 2 + 1) * 64 + lane];
        bf16x8 b0 = wp[(s * 4 + wv) * 64 + lane];
        acc0 = __builtin_amdgcn_mfma_f32_16x16x32_bf16(a0, b0, acc0, 0, 0, 0);
        acc1 = __builtin_amdgcn_mfma_f32_16x16x32_bf16(a1, b0, acc1, 0, 0, 0);
    }

    // -------- epilogue: C/D map col=lane&15 (=n), row=(lane>>4)*4+r (=m) --------
    int n = wv * 16 + (lane & 15);
    float bs = bias[n];
#pragma unroll
    for (int r = 0; r < 4; ++r) {
        int p0 = ((lane >> 4) << 2) + r;
        {
            int g = g0 + p0;
            int bb = g >> 14, ii = (g >> 7) & 127, jj = g & 127;
            out[((bb * COUT + n) * H_ + ii) * W_ + jj] = acc0[r] + bs;
        }
        {
            int g = g0 + 16 + p0;
            int bb = g >> 14, ii = (g >> 7) & 127, jj = g & 127;
            out[((bb * COUT + n) * H_ + ii) * W_ + jj] = acc1[r] + bs;
        }
    }
}

extern "C" void kernel_launch(void* const* d_in, const int* in_sizes, int n_in,
                              void* d_out, int out_size, void* d_ws, size_t ws_size,
                              hipStream_t stream) {
    const float* x      = (const float*)d_in[0];
    const float* offset = (const float*)d_in[1];
    const float* mask   = (const float*)d_in[2];
    const float* weight = (const float*)d_in[3];
    const float* bias   = (const float*)d_in[4];
    float* out = (float*)d_out;
    unsigned short* xt  = (unsigned short*)d_ws;
    unsigned short* wtf = xt + (size_t)B_ * H_ * W_ * CIN;   // +8 MB

    k_transpose<<<B_ * H_, 256, 0, stream>>>(x, xt);
    k_weight<<<144, 256, 0, stream>>>(weight, wtf);
    k_main<<<NBLK, 256, 0, stream>>>(xt, offset, mask, wtf, bias, out);
}